// Round 1
// baseline (281.098 us; speedup 1.0000x reference)
//
#include <hip/hip_runtime.h>
#include <hip/hip_bf16.h>

// Swin3D MHSA: B=256 windows, N=392 tokens, DIM=128, H=4 heads, dh=32.
// Strategy: bf16 MFMA (16x16x32) everywhere, f32 accumulate/softmax.
//   K1 bias:  materialize (H,392,392) f32 bias table (replicates torch quirk)
//   K2 qkv:   GEMM -> q (scaled), k as (B,H,N,32) bf16; v transposed (B,H,32,N)
//   K3 attn:  per (b,h) workgroup, full-row softmax in registers
//   K4 proj:  GEMM -> f32 out

typedef __attribute__((ext_vector_type(8))) short bf16x8;
typedef __attribute__((ext_vector_type(4))) float f32x4;
typedef __attribute__((ext_vector_type(4))) short s16x4;

#define NTOK 392
#define NN (NTOK * NTOK)   // 153664
#define TABLE 2535         // 15*13*13
#define SCALE 0.17677669529663689f  // 1/sqrt(32)

__device__ __forceinline__ unsigned short f2bf(float f) {
  union { float f; unsigned u; } v; v.f = f;
  unsigned r = v.u + 0x7FFFu + ((v.u >> 16) & 1u);
  return (unsigned short)(r >> 16);
}

// ---------------- K1: bias materialization ----------------
__global__ __launch_bounds__(256) void bias_kernel(
    const float* __restrict__ rpb, const int* __restrict__ relidx,
    float* __restrict__ biasbuf) {
  int g = blockIdx.x * 256 + threadIdx.x;  // over 4*392*392 = 614656
  if (g >= 4 * NN) return;
  int h = g / NN;
  int rem = g - h * NN;
  int i = rem / NTOK;
  int j = rem - i * NTOK;
  int f = i * (NTOK * 4) + j * 4 + h;      // flat index in (n, n, H) raw reshape
  int hs = f / NN;
  int p = f - hs * NN;
  biasbuf[g] = rpb[hs * TABLE + relidx[p]];
}

// ---------------- K2: QKV projection ----------------
__global__ __launch_bounds__(256) void qkv_kernel(
    const float* __restrict__ hidden, const float* __restrict__ Wqkv,
    const float* __restrict__ bqkv,
    unsigned short* __restrict__ qbuf, unsigned short* __restrict__ kbuf,
    unsigned short* __restrict__ vtbuf) {
  __shared__ unsigned short Ash[64][136];   // 64 tokens x 128 k, pad->2-way max
  __shared__ unsigned short Wsh[128][136];  // 128 out-features x 128 k
  const int tid = threadIdx.x;
  const int s = blockIdx.x;     // 0=q 1=k 2=v   (fast dim for L2 reuse of A)
  const int mblk = blockIdx.y;  // 0..1567

  for (int i = tid; i < 2048; i += 256) {   // A: 64*128 f32 = 2048 float4
    int row = i >> 5, c4 = i & 31;
    f32x4 v = *(const f32x4*)(hidden + ((size_t)mblk * 64 + row) * 128 + c4 * 4);
    s16x4 o;
    o[0] = (short)f2bf(v[0]); o[1] = (short)f2bf(v[1]);
    o[2] = (short)f2bf(v[2]); o[3] = (short)f2bf(v[3]);
    *(s16x4*)&Ash[row][c4 * 4] = o;
  }
  for (int i = tid; i < 4096; i += 256) {   // W slice: 128*128 f32
    int row = i >> 5, c4 = i & 31;
    f32x4 v = *(const f32x4*)(Wqkv + ((size_t)s * 128 + row) * 128 + c4 * 4);
    s16x4 o;
    o[0] = (short)f2bf(v[0]); o[1] = (short)f2bf(v[1]);
    o[2] = (short)f2bf(v[2]); o[3] = (short)f2bf(v[3]);
    *(s16x4*)&Wsh[row][c4 * 4] = o;
  }
  __syncthreads();

  const int w = tid >> 6, lane = tid & 63, l15 = lane & 15, lhi = lane >> 4;
  f32x4 acc[8];
#pragma unroll
  for (int jt = 0; jt < 8; ++jt) acc[jt] = 0.0f;
#pragma unroll
  for (int kk = 0; kk < 4; ++kk) {
    bf16x8 a = *(const bf16x8*)&Ash[w * 16 + l15][kk * 32 + lhi * 8];
#pragma unroll
    for (int jt = 0; jt < 8; ++jt) {
      bf16x8 bfr = *(const bf16x8*)&Wsh[jt * 16 + l15][kk * 32 + lhi * 8];
      acc[jt] = __builtin_amdgcn_mfma_f32_16x16x32_bf16(a, bfr, acc[jt], 0, 0, 0);
    }
  }
  const int t0 = mblk * 64 + w * 16 + lhi * 4;  // multiple of 4; 392%4==0 -> same b
  const int bb = t0 / 392;
  const int nn0 = t0 - bb * 392;
#pragma unroll
  for (int jt = 0; jt < 8; ++jt) {
    int colL = jt * 16 + l15;
    float bias = bqkv[s * 128 + colL];
    int hh = colL >> 5, dd = colL & 31;
    if (s == 2) {
      s16x4 o;
#pragma unroll
      for (int r = 0; r < 4; ++r) o[r] = (short)f2bf(acc[jt][r] + bias);
      *(s16x4*)&vtbuf[(((size_t)bb * 4 + hh) * 32 + dd) * NTOK + nn0] = o;
    } else {
      unsigned short* dst = (s == 0) ? qbuf : kbuf;
      float mul = (s == 0) ? SCALE : 1.0f;
#pragma unroll
      for (int r = 0; r < 4; ++r)
        dst[(((size_t)bb * 4 + hh) * NTOK + nn0 + r) * 32 + dd] =
            f2bf((acc[jt][r] + bias) * mul);
    }
  }
}

// ---------------- K3: attention ----------------
__global__ __launch_bounds__(256) void attn_kernel(
    const unsigned short* __restrict__ qbuf, const unsigned short* __restrict__ kbuf,
    const unsigned short* __restrict__ vtbuf, const float* __restrict__ biasbuf,
    unsigned short* __restrict__ ctxbuf) {
  __shared__ unsigned short Ksh[400][40];    // keys x dh, pad stride 40 (2-way max)
  __shared__ unsigned short Vtsh[32][424];   // dh x keys (padded to 424)
  __shared__ unsigned short Psh[4][16][40];  // per-wave P relayout buffer

  const int tid = threadIdx.x;
  const int w = tid >> 6, lane = tid & 63;
  const int l15 = lane & 15, lhi = lane >> 4;
  const int bh = blockIdx.x;  // b*4 + h
  const int h = bh & 3;
  const int b = bh >> 2;
  const size_t base = (size_t)bh * (NTOK * 32);

  for (int i = tid; i < 3136; i += 256) {  // K: 392*32/4 ushort4 chunks
    int row = i >> 3, c4 = i & 7;
    *(s16x4*)&Ksh[row][c4 * 4] = *(const s16x4*)(kbuf + base + (size_t)i * 4);
  }
  {  // zero K pad rows 392..399
    int row = 392 + (tid >> 5), col = tid & 31;
    Ksh[row][col] = 0;
  }
  for (int i = tid; i < 3136; i += 256) {  // Vt: 32 rows x 392
    int row = i / 98, c4 = i - row * 98;
    *(s16x4*)&Vtsh[row][c4 * 4] =
        *(const s16x4*)(vtbuf + base + (size_t)row * NTOK + c4 * 4);
  }
  for (int i = tid; i < 1024; i += 256) {  // zero Vt pad cols 392..423
    int row = i >> 5;
    Vtsh[row][392 + (i & 31)] = 0;
  }
  __syncthreads();

  const float* bias_h = biasbuf + (size_t)h * NN;

  for (int rb = w; rb < 25; rb += 4) {
    int qrow = rb * 16 + l15;
    if (qrow > 391) qrow = 391;  // duplicate row; outputs masked at write
    bf16x8 qf = *(const bf16x8*)(qbuf + base + (size_t)qrow * 32 + lhi * 8);

    float p[25][4];
#pragma unroll
    for (int jt = 0; jt < 25; ++jt) {
      f32x4 acc = 0.0f;
      bf16x8 kf = *(const bf16x8*)&Ksh[jt * 16 + l15][lhi * 8];
      acc = __builtin_amdgcn_mfma_f32_16x16x32_bf16(qf, kf, acc, 0, 0, 0);
      int col = jt * 16 + l15;
      bool cv = (col < NTOK);
#pragma unroll
      for (int r = 0; r < 4; ++r) {
        int row = rb * 16 + lhi * 4 + r;
        if (row > 391) row = 391;
        p[jt][r] = cv ? (acc[r] + bias_h[(size_t)row * NTOK + col]) : -1e30f;
      }
    }
    // softmax (rows live across 16 lanes sharing lhi; reduce with xor 1,2,4,8)
    float m[4], ls[4], rinv[4];
#pragma unroll
    for (int r = 0; r < 4; ++r) {
      float mx = p[0][r];
#pragma unroll
      for (int jt = 1; jt < 25; ++jt) mx = fmaxf(mx, p[jt][r]);
      m[r] = mx;
    }
#pragma unroll
    for (int off = 1; off < 16; off <<= 1)
#pragma unroll
      for (int r = 0; r < 4; ++r) m[r] = fmaxf(m[r], __shfl_xor(m[r], off));
#pragma unroll
    for (int r = 0; r < 4; ++r) ls[r] = 0.f;
#pragma unroll
    for (int jt = 0; jt < 25; ++jt)
#pragma unroll
      for (int r = 0; r < 4; ++r) {
        float e = __expf(p[jt][r] - m[r]);
        p[jt][r] = e;
        ls[r] += e;
      }
#pragma unroll
    for (int off = 1; off < 16; off <<= 1)
#pragma unroll
      for (int r = 0; r < 4; ++r) ls[r] += __shfl_xor(ls[r], off);
#pragma unroll
    for (int r = 0; r < 4; ++r) rinv[r] = 1.f / ls[r];

    // PV: 13 groups of 32 keys; P relayout via per-wave LDS buffer
    f32x4 acc2[2];
    acc2[0] = 0.0f; acc2[1] = 0.0f;
#pragma unroll
    for (int kk = 0; kk < 13; ++kk) {
#pragma unroll
      for (int r = 0; r < 4; ++r) {
        int prow = lhi * 4 + r;
        Psh[w][prow][l15] = f2bf(p[2 * kk][r]);
        Psh[w][prow][16 + l15] =
            (2 * kk + 1 < 25) ? f2bf(p[2 * kk + 1][r]) : (unsigned short)0;
      }
      bf16x8 pf = *(const bf16x8*)&Psh[w][l15][lhi * 8];
#pragma unroll
      for (int hn = 0; hn < 2; ++hn) {
        bf16x8 vf = *(const bf16x8*)&Vtsh[hn * 16 + l15][kk * 32 + lhi * 8];
        acc2[hn] = __builtin_amdgcn_mfma_f32_16x16x32_bf16(pf, vf, acc2[hn], 0, 0, 0);
      }
    }
#pragma unroll
    for (int hn = 0; hn < 2; ++hn)
#pragma unroll
      for (int r = 0; r < 4; ++r) {
        int row = rb * 16 + lhi * 4 + r;
        if (row < NTOK) {
          int d = hn * 16 + l15;
          ctxbuf[((size_t)(b * NTOK) + row) * 128 + h * 32 + d] =
              f2bf(acc2[hn][r] * rinv[r]);
        }
      }
  }
}

// ---------------- K4: output projection ----------------
__global__ __launch_bounds__(256) void proj_kernel(
    const unsigned short* __restrict__ ctxbuf, const float* __restrict__ Wp,
    const float* __restrict__ bp, float* __restrict__ out) {
  __shared__ unsigned short Ash[64][136];
  __shared__ unsigned short Wsh[128][136];
  const int tid = threadIdx.x;
  const int mblk = blockIdx.x;

  for (int i = tid; i < 1024; i += 256) {  // A: 64*128 bf16 as 16B chunks
    int row = i >> 4, c8 = i & 15;
    *(bf16x8*)&Ash[row][c8 * 8] =
        *(const bf16x8*)(ctxbuf + ((size_t)mblk * 64 + row) * 128 + c8 * 8);
  }
  for (int i = tid; i < 4096; i += 256) {  // W: 128*128 f32
    int row = i >> 5, c4 = i & 31;
    f32x4 v = *(const f32x4*)(Wp + (size_t)row * 128 + c4 * 4);
    s16x4 o;
    o[0] = (short)f2bf(v[0]); o[1] = (short)f2bf(v[1]);
    o[2] = (short)f2bf(v[2]); o[3] = (short)f2bf(v[3]);
    *(s16x4*)&Wsh[row][c4 * 4] = o;
  }
  __syncthreads();

  const int w = tid >> 6, lane = tid & 63, l15 = lane & 15, lhi = lane >> 4;
  f32x4 acc[8];
#pragma unroll
  for (int jt = 0; jt < 8; ++jt) acc[jt] = 0.0f;
#pragma unroll
  for (int kk = 0; kk < 4; ++kk) {
    bf16x8 a = *(const bf16x8*)&Ash[w * 16 + l15][kk * 32 + lhi * 8];
#pragma unroll
    for (int jt = 0; jt < 8; ++jt) {
      bf16x8 bfr = *(const bf16x8*)&Wsh[jt * 16 + l15][kk * 32 + lhi * 8];
      acc[jt] = __builtin_amdgcn_mfma_f32_16x16x32_bf16(a, bfr, acc[jt], 0, 0, 0);
    }
  }
#pragma unroll
  for (int jt = 0; jt < 8; ++jt) {
    int colL = jt * 16 + l15;
    float bias = bp[colL];
#pragma unroll
    for (int r = 0; r < 4; ++r) {
      int t = mblk * 64 + w * 16 + lhi * 4 + r;
      out[(size_t)t * 128 + colL] = acc[jt][r] + bias;
    }
  }
}

// ---------------- launch ----------------
extern "C" void kernel_launch(void* const* d_in, const int* in_sizes, int n_in,
                              void* d_out, int out_size, void* d_ws, size_t ws_size,
                              hipStream_t stream) {
  const float* hidden = (const float*)d_in[0];
  const float* Wqkv = (const float*)d_in[1];
  const float* bqkv = (const float*)d_in[2];
  const float* Wp = (const float*)d_in[3];
  const float* bp = (const float*)d_in[4];
  const float* rpb = (const float*)d_in[5];
  const int* relidx = (const int*)d_in[6];

  // ws layout (needs ~105.3 MB): q | k | vt | ctx (bf16, 12,845,056 elems each)
  // then bias (614,656 f32)
  unsigned short* qbuf = (unsigned short*)d_ws;
  unsigned short* kbuf = qbuf + 12845056;
  unsigned short* vtbuf = kbuf + 12845056;
  unsigned short* ctxbuf = vtbuf + 12845056;
  float* biasbuf = (float*)(ctxbuf + 12845056);

  bias_kernel<<<2401, 256, 0, stream>>>(rpb, relidx, biasbuf);
  qkv_kernel<<<dim3(3, 1568), 256, 0, stream>>>(hidden, Wqkv, bqkv, qbuf, kbuf, vtbuf);
  attn_kernel<<<1024, 256, 0, stream>>>(qbuf, kbuf, vtbuf, biasbuf, ctxbuf);
  proj_kernel<<<1568, 256, 0, stream>>>(ctxbuf, Wp, bp, (float*)d_out);
}

// Round 2
// 191.977 us; speedup vs baseline: 1.4642x; 1.4642x over previous
//
#include <hip/hip_runtime.h>
#include <hip/hip_bf16.h>

// Swin3D MHSA: B=256 windows, N=392 tokens, DIM=128, H=4 heads, dh=32.
// R2: swapped-QK^T attention (S^T via mfma(K,Q)) -> lane-local softmax rows,
//     bias precomputed in MFMA lane layout (bf16, 8B/lane loads),
//     V read from L2 (no LDS stage), Psh as packed u32 b64 writes.

typedef __attribute__((ext_vector_type(8))) short bf16x8;
typedef __attribute__((ext_vector_type(4))) float f32x4;
typedef __attribute__((ext_vector_type(4))) short s16x4;
typedef __attribute__((ext_vector_type(2))) unsigned int u32x2;

#define NTOK 392
#define NN (NTOK * NTOK)   // 153664
#define TABLE 2535         // 15*13*13
#define SCALE 0.17677669529663689f  // 1/sqrt(32)

__device__ __forceinline__ unsigned short f2bf(float f) {
  union { float f; unsigned u; } v; v.f = f;
  unsigned r = v.u + 0x7FFFu + ((v.u >> 16) & 1u);
  return (unsigned short)(r >> 16);
}
__device__ __forceinline__ float b2f(short s) {
  union { unsigned u; float f; } v;
  v.u = ((unsigned)(unsigned short)s) << 16;
  return v.f;
}
__device__ __forceinline__ unsigned pk2(float lo, float hi) {
  return (unsigned)f2bf(lo) | ((unsigned)f2bf(hi) << 16);
}

// ---------------- K1: bias in MFMA lane layout ----------------
// biaspre[h][rb=25][jt=25][lane=64][r=4] bf16, value = bias[q][k] with
// q = rb*16 + (lane&15), k = jt*16 + (lane>>4)*4 + r   (clamped; OOB masked later)
__global__ __launch_bounds__(256) void biaspre_kernel(
    const float* __restrict__ rpb, const int* __restrict__ relidx,
    unsigned short* __restrict__ biaspre) {
  int g = blockIdx.x * 256 + threadIdx.x;  // 4*25*25*256 = 640000
  if (g >= 640000) return;
  int r = g & 3, lane = (g >> 2) & 63;
  int t = g >> 8;
  int jt = t % 25; int t2 = t / 25;
  int rb = t2 % 25; int h = t2 / 25;
  int q = rb * 16 + (lane & 15); if (q > 391) q = 391;
  int k = jt * 16 + (lane >> 4) * 4 + r; if (k > 391) k = 391;
  int f = q * (NTOK * 4) + k * 4 + h;   // raw (n,n,H) reshape quirk
  int hs = f / NN; int p = f - hs * NN;
  biaspre[g] = f2bf(rpb[hs * TABLE + relidx[p]]);
}

// ---------------- K2: QKV projection (A staged once, loop over q/k/v) -------
__global__ __launch_bounds__(256) void qkv_kernel(
    const float* __restrict__ hidden, const float* __restrict__ Wqkv,
    const float* __restrict__ bqkv,
    unsigned short* __restrict__ qbuf, unsigned short* __restrict__ kbuf,
    unsigned short* __restrict__ vtbuf) {
  __shared__ unsigned short Ash[64][136];
  __shared__ unsigned short Wsh[128][136];
  const int tid = threadIdx.x;
  const int mblk = blockIdx.x;  // 0..1567

  for (int i = tid; i < 2048; i += 256) {   // A: 64*128 f32
    int row = i >> 5, c4 = i & 31;
    f32x4 v = *(const f32x4*)(hidden + ((size_t)mblk * 64 + row) * 128 + c4 * 4);
    s16x4 o;
    o[0] = (short)f2bf(v[0]); o[1] = (short)f2bf(v[1]);
    o[2] = (short)f2bf(v[2]); o[3] = (short)f2bf(v[3]);
    *(s16x4*)&Ash[row][c4 * 4] = o;
  }

  const int w = tid >> 6, lane = tid & 63, l15 = lane & 15, lhi = lane >> 4;
  const int t0 = mblk * 64 + w * 16 + lhi * 4;  // 392%4==0 -> run stays in one b
  const int bb = t0 / 392;
  const int nn0 = t0 - bb * 392;

  for (int s = 0; s < 3; ++s) {
    __syncthreads();  // covers A-stage (s=0) and protects Wsh reuse (s>0)
    for (int i = tid; i < 4096; i += 256) {   // W slice: 128*128 f32
      int row = i >> 5, c4 = i & 31;
      f32x4 v = *(const f32x4*)(Wqkv + ((size_t)s * 128 + row) * 128 + c4 * 4);
      s16x4 o;
      o[0] = (short)f2bf(v[0]); o[1] = (short)f2bf(v[1]);
      o[2] = (short)f2bf(v[2]); o[3] = (short)f2bf(v[3]);
      *(s16x4*)&Wsh[row][c4 * 4] = o;
    }
    __syncthreads();

    f32x4 acc[8];
#pragma unroll
    for (int jt = 0; jt < 8; ++jt) acc[jt] = 0.0f;
#pragma unroll
    for (int kk = 0; kk < 4; ++kk) {
      bf16x8 a = *(const bf16x8*)&Ash[w * 16 + l15][kk * 32 + lhi * 8];
#pragma unroll
      for (int jt = 0; jt < 8; ++jt) {
        bf16x8 bfr = *(const bf16x8*)&Wsh[jt * 16 + l15][kk * 32 + lhi * 8];
        acc[jt] = __builtin_amdgcn_mfma_f32_16x16x32_bf16(a, bfr, acc[jt], 0, 0, 0);
      }
    }
#pragma unroll
    for (int jt = 0; jt < 8; ++jt) {
      int colL = jt * 16 + l15;
      float bias = bqkv[s * 128 + colL];
      int hh = colL >> 5, dd = colL & 31;
      if (s == 2) {
        s16x4 o;
#pragma unroll
        for (int r = 0; r < 4; ++r) o[r] = (short)f2bf(acc[jt][r] + bias);
        *(s16x4*)&vtbuf[(((size_t)bb * 4 + hh) * 32 + dd) * NTOK + nn0] = o;
      } else {
        unsigned short* dst = (s == 0) ? qbuf : kbuf;
        float mul = (s == 0) ? SCALE : 1.0f;
#pragma unroll
        for (int r = 0; r < 4; ++r)
          dst[(((size_t)bb * 4 + hh) * NTOK + nn0 + r) * 32 + dd] =
              f2bf((acc[jt][r] + bias) * mul);
      }
    }
  }
}

// ---------------- K3: attention (swapped QK^T) ----------------
__global__ __launch_bounds__(256, 4) void attn_kernel(
    const unsigned short* __restrict__ qbuf, const unsigned short* __restrict__ kbuf,
    const unsigned short* __restrict__ vtbuf, const unsigned short* __restrict__ biaspre,
    unsigned short* __restrict__ ctxbuf) {
  __shared__ unsigned short Ksh[400][40];   // 32.0 KB, keys x dh
  __shared__ unsigned int Psh[4][16][20];   // 5.1 KB per-wave P tiles (stride 80B)

  const int tid = threadIdx.x;
  const int w = tid >> 6, lane = tid & 63;
  const int l15 = lane & 15, lhi = lane >> 4;
  const int bh = blockIdx.x;
  const int h = bh & 3, b = bh >> 2;
  const size_t base = (size_t)bh * (NTOK * 32);

  for (int i = tid; i < 3136; i += 256) {
    int row = i >> 3, c4 = i & 7;
    *(s16x4*)&Ksh[row][c4 * 4] = *(const s16x4*)(kbuf + base + (size_t)i * 4);
  }
  { int row = 392 + (tid >> 5); Ksh[row][tid & 31] = 0; }  // zero pad rows
  __syncthreads();

  const unsigned short* vbase = vtbuf + base;
  const s16x4* bias_lane =
      (const s16x4*)(biaspre + (size_t)h * 25 * 25 * 256 + (size_t)lane * 4);

  for (int rb = w; rb < 25; rb += 4) {
    int qrow = rb * 16 + l15; if (qrow > 391) qrow = 391;
    bf16x8 qf = *(const bf16x8*)(qbuf + base + (size_t)qrow * 32 + lhi * 8);
    const s16x4* bp = bias_lane + (size_t)rb * 25 * 64;  // +jt*64 per jt

    f32x4 o0 = 0.0f, o1 = 0.0f;
    float ssum = 0.f;

    for (int g = 0; g < 12; ++g) {  // jt pairs (2g, 2g+1), all k valid
      int jt0 = 2 * g, jt1 = 2 * g + 1;
      bf16x8 kf0 = *(const bf16x8*)&Ksh[jt0 * 16 + l15][lhi * 8];
      bf16x8 kf1 = *(const bf16x8*)&Ksh[jt1 * 16 + l15][lhi * 8];
      f32x4 s0 = __builtin_amdgcn_mfma_f32_16x16x32_bf16(kf0, qf, (f32x4)0.f, 0, 0, 0);
      f32x4 s1 = __builtin_amdgcn_mfma_f32_16x16x32_bf16(kf1, qf, (f32x4)0.f, 0, 0, 0);
      s16x4 bv0 = bp[jt0 * 64];
      s16x4 bv1 = bp[jt1 * 64];
      float e00 = __expf(s0[0] + b2f(bv0[0])), e01 = __expf(s0[1] + b2f(bv0[1]));
      float e02 = __expf(s0[2] + b2f(bv0[2])), e03 = __expf(s0[3] + b2f(bv0[3]));
      float e10 = __expf(s1[0] + b2f(bv1[0])), e11 = __expf(s1[1] + b2f(bv1[1]));
      float e12 = __expf(s1[2] + b2f(bv1[2])), e13 = __expf(s1[3] + b2f(bv1[3]));
      ssum += (e00 + e01 + e02 + e03) + (e10 + e11 + e12 + e13);
      u32x2 wlo; wlo[0] = pk2(e00, e01); wlo[1] = pk2(e02, e03);
      u32x2 whi; whi[0] = pk2(e10, e11); whi[1] = pk2(e12, e13);
      *(u32x2*)&Psh[w][l15][lhi * 2] = wlo;       // k cols lhi*4..+3
      *(u32x2*)&Psh[w][l15][8 + lhi * 2] = whi;   // k cols 16+lhi*4..+3
      bf16x8 pf = *(const bf16x8*)&Psh[w][l15][lhi * 4];
      bf16x8 vf0 = *(const bf16x8*)(vbase + (size_t)l15 * NTOK + g * 32 + lhi * 8);
      bf16x8 vf1 = *(const bf16x8*)(vbase + (size_t)(16 + l15) * NTOK + g * 32 + lhi * 8);
      o0 = __builtin_amdgcn_mfma_f32_16x16x32_bf16(pf, vf0, o0, 0, 0, 0);
      o1 = __builtin_amdgcn_mfma_f32_16x16x32_bf16(pf, vf1, o1, 0, 0, 0);
    }
    {  // g = 12: jt0 = 24 (k 384..391 valid only for lhi<2), jt1 absent
      bf16x8 kf0 = *(const bf16x8*)&Ksh[384 + l15][lhi * 8];
      f32x4 s0 = __builtin_amdgcn_mfma_f32_16x16x32_bf16(kf0, qf, (f32x4)0.f, 0, 0, 0);
      s16x4 bv0 = bp[24 * 64];
      float e00 = __expf(s0[0] + b2f(bv0[0])), e01 = __expf(s0[1] + b2f(bv0[1]));
      float e02 = __expf(s0[2] + b2f(bv0[2])), e03 = __expf(s0[3] + b2f(bv0[3]));
      if (lhi >= 2) { e00 = 0.f; e01 = 0.f; e02 = 0.f; e03 = 0.f; }
      ssum += (e00 + e01) + (e02 + e03);
      u32x2 wlo; wlo[0] = pk2(e00, e01); wlo[1] = pk2(e02, e03);
      u32x2 whi; whi[0] = 0u; whi[1] = 0u;
      *(u32x2*)&Psh[w][l15][lhi * 2] = wlo;
      *(u32x2*)&Psh[w][l15][8 + lhi * 2] = whi;
      bf16x8 pf = *(const bf16x8*)&Psh[w][l15][lhi * 4];
      bf16x8 vf0 = *(const bf16x8*)(vbase + (size_t)l15 * NTOK + 384 + lhi * 8);
      bf16x8 vf1 = *(const bf16x8*)(vbase + (size_t)(16 + l15) * NTOK + 384 + lhi * 8);
      o0 = __builtin_amdgcn_mfma_f32_16x16x32_bf16(pf, vf0, o0, 0, 0, 0);
      o1 = __builtin_amdgcn_mfma_f32_16x16x32_bf16(pf, vf1, o1, 0, 0, 0);
    }

    // total row sums: lanes sharing l15 (stride 16) hold partials
    ssum += __shfl_xor(ssum, 16);
    ssum += __shfl_xor(ssum, 32);
    float rtot = 1.f / ssum;   // valid for q-row = l15 (all lhi copies)
    float rr[4];
#pragma unroll
    for (int r = 0; r < 4; ++r) rr[r] = __shfl(rtot, lhi * 4 + r);

#pragma unroll
    for (int r = 0; r < 4; ++r) {
      int row = rb * 16 + lhi * 4 + r;
      if (row < NTOK) {
        unsigned short* crow = ctxbuf + ((size_t)(b * NTOK) + row) * 128 + h * 32;
        crow[l15] = f2bf(o0[r] * rr[r]);
        crow[16 + l15] = f2bf(o1[r] * rr[r]);
      }
    }
  }
}

// ---------------- K4: output projection ----------------
__global__ __launch_bounds__(256) void proj_kernel(
    const unsigned short* __restrict__ ctxbuf, const float* __restrict__ Wp,
    const float* __restrict__ bp, float* __restrict__ out) {
  __shared__ unsigned short Ash[64][136];
  __shared__ unsigned short Wsh[128][136];
  const int tid = threadIdx.x;
  const int mblk = blockIdx.x;

  for (int i = tid; i < 1024; i += 256) {
    int row = i >> 4, c8 = i & 15;
    *(bf16x8*)&Ash[row][c8 * 8] =
        *(const bf16x8*)(ctxbuf + ((size_t)mblk * 64 + row) * 128 + c8 * 8);
  }
  for (int i = tid; i < 4096; i += 256) {
    int row = i >> 5, c4 = i & 31;
    f32x4 v = *(const f32x4*)(Wp + (size_t)row * 128 + c4 * 4);
    s16x4 o;
    o[0] = (short)f2bf(v[0]); o[1] = (short)f2bf(v[1]);
    o[2] = (short)f2bf(v[2]); o[3] = (short)f2bf(v[3]);
    *(s16x4*)&Wsh[row][c4 * 4] = o;
  }
  __syncthreads();

  const int w = tid >> 6, lane = tid & 63, l15 = lane & 15, lhi = lane >> 4;
  f32x4 acc[8];
#pragma unroll
  for (int jt = 0; jt < 8; ++jt) acc[jt] = 0.0f;
#pragma unroll
  for (int kk = 0; kk < 4; ++kk) {
    bf16x8 a = *(const bf16x8*)&Ash[w * 16 + l15][kk * 32 + lhi * 8];
#pragma unroll
    for (int jt = 0; jt < 8; ++jt) {
      bf16x8 bfr = *(const bf16x8*)&Wsh[jt * 16 + l15][kk * 32 + lhi * 8];
      acc[jt] = __builtin_amdgcn_mfma_f32_16x16x32_bf16(a, bfr, acc[jt], 0, 0, 0);
    }
  }
#pragma unroll
  for (int jt = 0; jt < 8; ++jt) {
    int colL = jt * 16 + l15;
    float bias = bp[colL];
#pragma unroll
    for (int r = 0; r < 4; ++r) {
      int t = mblk * 64 + w * 16 + lhi * 4 + r;
      out[(size_t)t * 128 + colL] = acc[jt][r] + bias;
    }
  }
}

// ---------------- launch ----------------
extern "C" void kernel_launch(void* const* d_in, const int* in_sizes, int n_in,
                              void* d_out, int out_size, void* d_ws, size_t ws_size,
                              hipStream_t stream) {
  const float* hidden = (const float*)d_in[0];
  const float* Wqkv = (const float*)d_in[1];
  const float* bqkv = (const float*)d_in[2];
  const float* Wp = (const float*)d_in[3];
  const float* bp = (const float*)d_in[4];
  const float* rpb = (const float*)d_in[5];
  const int* relidx = (const int*)d_in[6];

  // ws: q | k | vt(+pad) | ctx (bf16, 12,845,056 each) | biaspre (640,000 bf16)
  unsigned short* qbuf = (unsigned short*)d_ws;
  unsigned short* kbuf = qbuf + 12845056;
  unsigned short* vtbuf = kbuf + 12845056;
  unsigned short* ctxbuf = vtbuf + 12845056 + 1024;  // pad: attn V reads overshoot
  unsigned short* biaspre = ctxbuf + 12845056;

  biaspre_kernel<<<2500, 256, 0, stream>>>(rpb, relidx, biaspre);
  qkv_kernel<<<1568, 256, 0, stream>>>(hidden, Wqkv, bqkv, qbuf, kbuf, vtbuf);
  attn_kernel<<<1024, 256, 0, stream>>>(qbuf, kbuf, vtbuf, biaspre, ctxbuf);
  proj_kernel<<<1568, 256, 0, stream>>>(ctxbuf, Wp, bp, (float*)d_out);
}